// Round 6
// baseline (17204.498 us; speedup 1.0000x reference)
//
#include <hip/hip_runtime.h>

typedef short short8 __attribute__((ext_vector_type(8)));
typedef float f32x4 __attribute__((ext_vector_type(4)));
typedef unsigned short u16;
typedef unsigned int u32;

#define C64 64
#define HWp (512*512)
#define NWG 64
#define PR 72      // LDS row stride in u16 (144 B, 16B-aligned, 2-way-free banks)
#define NROW 64    // rows computed per step (4 MFMA M-tiles)
#define SLOTS 50   // state rows: absrows a-8 .. a+41 (same window as round 5)
#define T7 7       // columns per epoch (511 = 7*73)
#define NEP 73

struct Ws {
  int flags[NWG];            // epoch counter per band (-1 = not posted)
  int _pad[64];
  u32 haloT[NWG][2][8*64];   // band's owned rows absr a..a+7, f32 bits
  u32 haloB[NWG][2][7*64];   // band's owned rows absr a+25..a+31, f32 bits
};

__device__ __forceinline__ u16 f2bf(float f){
  u32 u = __float_as_uint(f);
  u += 0x7fffu + ((u >> 16) & 1u);
  return (u16)(u >> 16);
}
__device__ __forceinline__ float bf2f(u16 h){ return __uint_as_float(((u32)h) << 16); }
__device__ __forceinline__ f32x4 splat4(float x){ f32x4 v = {x,x,x,x}; return v; }
__device__ __forceinline__ float sigm(float x){ return 1.f/(1.f + __expf(-x)); }
__device__ __forceinline__ float tanh_(float x){ float e = __expf(2.f*x); return 1.f - 2.f/(e + 1.f); }

#define MFMA16(a,b,c) __builtin_amdgcn_mfma_f32_16x16x32_bf16(a,b,c,0,0,0)
#define ATOM_ST(p,v) __hip_atomic_store((p),(v),__ATOMIC_RELAXED,__HIP_MEMORY_SCOPE_AGENT)
#define ATOM_LD(p)   __hip_atomic_load((p),__ATOMIC_RELAXED,__HIP_MEMORY_SCOPE_AGENT)
// 3-term hi/lo product (drops Al*Bl: ~1e-6 contribution, negligible)
#define DOT3(acc, XH, XL, WH, WL) \
  acc = MFMA16(XH, WH, acc); acc = MFMA16(XL, WH, acc); acc = MFMA16(XH, WL, acc);

__global__ void reset_flags(int* flags) {
  if (threadIdx.x < NWG) flags[threadIdx.x] = -1;
}

__global__ __launch_bounds__(512, 2)
void gru_scan(const float* __restrict__ feat,
              const float* __restrict__ w_ih,
              const float* __restrict__ w_hh,
              const float* __restrict__ b_ih,
              const float* __restrict__ b_hh,
              float* __restrict__ out,
              Ws* __restrict__ ws)
{
  // state slot s = absrow (a-8+s), s=0..49, hi/lo bf16 planes
  __shared__ __align__(16) u16 sh[SLOTS*PR], sl[SLOTS*PR];
  // current feat column, rows m=0..63 (absrow a-15+m), hi/lo bf16
  __shared__ __align__(16) u16 uh[NROW*PR], ul[NROW*PR];
  // output stage: [owned row 0..31][col 0..6][ch 0..63] bf16
  __shared__ u16 ostage[32*T7*64];

  const int tid  = threadIdx.x;
  const int wg   = blockIdx.x;
  const int b    = wg >> 4;
  const int kband= wg & 15;
  const int a    = kband * 32;          // first owned row
  const int lane = tid & 63;
  const int wid  = tid >> 6;            // 0..7
  const int rg   = wid >> 2;            // row-group: tiles 2rg, 2rg+1
  const int q    = wid & 3;             // ch-quarter
  const int ln16 = lane & 15;
  const int kgrp = lane >> 4;
  const int ch   = q*16 + ln16;         // output channel of this thread

  // ---- weights (hi+lo) in registers ----
  short8 BihH[3][6], BihL[3][6], BhhH[3][2], BhhL[3][2];
#pragma unroll
  for (int g = 0; g < 3; ++g) {
    const int n = g*64 + ch;
#pragma unroll
    for (int kk = 0; kk < 6; ++kk) {
      short8 vh, vl;
#pragma unroll
      for (int j = 0; j < 8; ++j) {
        float wv = w_ih[n*192 + kk*32 + kgrp*8 + j];
        u16 h = f2bf(wv); vh[j] = (short)h; vl[j] = (short)f2bf(wv - bf2f(h));
      }
      BihH[g][kk] = vh; BihL[g][kk] = vl;
    }
#pragma unroll
    for (int kt = 0; kt < 2; ++kt) {
      short8 vh, vl;
#pragma unroll
      for (int j = 0; j < 8; ++j) {
        float wv = w_hh[n*64 + kt*32 + kgrp*8 + j];
        u16 h = f2bf(wv); vh[j] = (short)h; vl[j] = (short)f2bf(wv - bf2f(h));
      }
      BhhH[g][kt] = vh; BhhL[g][kt] = vl;
    }
  }
  const float biasR  = b_ih[ch]       + b_hh[ch];
  const float biasZ  = b_ih[64 + ch]  + b_hh[64 + ch];
  const float biasI  = b_ih[128 + ch];
  const float biasHn = b_hh[128 + ch];

  // ---- loader mapping: thread loads 8 rows of one channel ----
  const int lch = tid & 63;
  const int lr0 = (tid >> 6) * 8;
  const float* fbase = feat + (size_t)(b*C64 + lch)*HWp;

  // ---- init ----
  for (int i = tid; i < SLOTS*PR; i += 512) { sh[i] = 0; sl[i] = 0; }
  __syncthreads();
  // column 0 -> state slots + out passthrough; column 1 -> uh/ul
#pragma unroll
  for (int i = 0; i < 8; ++i) {
    const int m = lr0 + i, absr = a - 15 + m, s = m - 7;
    if ((unsigned)absr < 512u) {
      float v = fbase[(size_t)absr*512];
      if (s >= 0 && s < SLOTS) {
        u16 h_ = f2bf(v);
        sh[s*PR + lch] = h_;
        sl[s*PR + lch] = f2bf(v - bf2f(h_));
      }
      if (m >= 15 && m < 47) out[(size_t)(b*C64 + lch)*HWp + (size_t)absr*512] = v;
      float v1 = fbase[(size_t)absr*512 + 1];
      u16 h1 = f2bf(v1);
      uh[m*PR + lch] = h1;
      ul[m*PR + lch] = f2bf(v1 - bf2f(h1));
    } else {
      uh[m*PR + lch] = 0; ul[m*PR + lch] = 0;
    }
  }
  __syncthreads();

  // ---- epoch loop ----
  for (int e = 0; e < NEP; ++e) {
    const int par = e & 1;
#pragma unroll 1
    for (int d = 0; d < T7; ++d) {
      const int w = e*T7 + 1 + d;
      // prefetch feat column w+1 (consumed in writeback phase)
      float cv[8];
      {
        const int wn = (w < 511) ? w + 1 : 511;
#pragma unroll
        for (int i = 0; i < 8; ++i) {
          const int absr = a - 15 + lr0 + i;
          cv[i] = ((unsigned)absr < 512u) ? fbase[(size_t)absr*512 + wn] : 0.f;
        }
      }
      // ---- MFMA: 2 tiles per wave ----
      float hnv[2][4];
#pragma unroll
      for (int tt = 0; tt < 2; ++tt) {
        const int t = rg*2 + tt;
        f32x4 aR = splat4(biasR), aZ = splat4(biasZ);
        f32x4 aI = splat4(biasI), aH = splat4(biasHn);
        short8 Xh[2], Xl[2];
#pragma unroll
        for (int kt = 0; kt < 2; ++kt) {
          const int ro = (t*16 + ln16)*PR + kt*32 + kgrp*8;
          Xh[kt] = *(const short8*)&uh[ro];
          Xl[kt] = *(const short8*)&ul[ro];
        }
#pragma unroll
        for (int kk = 0; kk < 6; ++kk) {
          // state row for output row (t*16+ln16): slots m-8+delta, clamped into window
          int rr = t*16 + ln16 - 8 + (kk >> 1);
          rr = rr < 0 ? 0 : (rr > SLOTS-1 ? SLOTS-1 : rr);
          const int ro = rr*PR + (kk&1)*32 + kgrp*8;
          short8 Ah = *(const short8*)&sh[ro];
          short8 Al = *(const short8*)&sl[ro];
          DOT3(aR, Ah, Al, BihH[0][kk], BihL[0][kk]);
          DOT3(aZ, Ah, Al, BihH[1][kk], BihL[1][kk]);
          DOT3(aI, Ah, Al, BihH[2][kk], BihL[2][kk]);
        }
#pragma unroll
        for (int kt = 0; kt < 2; ++kt) {
          DOT3(aR, Xh[kt], Xl[kt], BhhH[0][kt], BhhL[0][kt]);
          DOT3(aZ, Xh[kt], Xl[kt], BhhH[1][kt], BhhL[1][kt]);
          DOT3(aH, Xh[kt], Xl[kt], BhhH[2][kt], BhhL[2][kt]);
        }
#pragma unroll
        for (int j = 0; j < 4; ++j) {
          const int m = t*16 + kgrp*4 + j;
          float r = sigm(aR[j]);
          float z = sigm(aZ[j]);
          float n = tanh_(aI[j] + r * aH[j]);
          float cur = bf2f(uh[m*PR + ch]) + bf2f(ul[m*PR + ch]);
          hnv[tt][j] = (1.f - z)*n + z*cur;
        }
      }
      __syncthreads();   // B2: all reads of sh/sl/uh/ul done

      // ---- writeback phase ----
#pragma unroll
      for (int tt = 0; tt < 2; ++tt)
#pragma unroll
        for (int j = 0; j < 4; ++j) {
          const int m = (rg*2 + tt)*16 + kgrp*4 + j;
          const int absr = a - 15 + m;
          const float v = hnv[tt][j];
          if ((unsigned)absr < 512u) {     // essential: keeps zero-pad rows zero
            const int s = m - 7;
            if (s >= 0 && s < SLOTS) {
              u16 h_ = f2bf(v);
              sh[s*PR + ch] = h_;
              sl[s*PR + ch] = f2bf(v - bf2f(h_));
            }
          }
          if (m >= 15 && m < 47)
            ostage[((m-15)*T7 + d)*64 + ch] = f2bf(v);
          if (d == T7-1 && e < NEP-1) {    // epoch-boundary halo send (exact f32)
            if (m >= 15 && m <= 22)        // absr a..a+7
              ATOM_ST(&ws->haloT[wg][par][(m-15)*64 + ch], __float_as_uint(v));
            if (m >= 40 && m <= 46)        // absr a+25..a+31
              ATOM_ST(&ws->haloB[wg][par][(m-40)*64 + ch], __float_as_uint(v));
          }
        }
      // uh/ul <- column w+1
#pragma unroll
      for (int i = 0; i < 8; ++i) {
        const int m = lr0 + i;
        u16 h_ = f2bf(cv[i]);
        uh[m*PR + lch] = h_;
        ul[m*PR + lch] = f2bf(cv[i] - bf2f(h_));
      }
      if (d < T7-1) __syncthreads();   // B1 of next step
    }

    // ---- epoch boundary ----
    asm volatile("s_waitcnt vmcnt(0)" ::: "memory");  // every wave drains halo sends
    __syncthreads();                                  // all drained + LDS wb done
    if (e < NEP-1 && tid == 0) ATOM_ST(&ws->flags[wg], e);

    if (wid == 1 && kband > 0 && e < NEP-1) {   // top halo <- up-neighbor's bottom rows
      int f = -1, guard = 0;
      while (f < e && ++guard < (1<<17)) {
        if (lane == 0) f = ATOM_LD(&ws->flags[wg-1]);
        f = __shfl(f, 0);
        if (f < e) __builtin_amdgcn_s_sleep(1);
      }
      asm volatile("" ::: "memory");
#pragma unroll
      for (int i = 0; i < 7; ++i) {
        // haloB[i] = absrow a-7+i -> slot 1+i
        float v = __uint_as_float(ATOM_LD(&ws->haloB[wg-1][par][i*64 + lane]));
        u16 h_ = f2bf(v);
        sh[(1+i)*PR + lane] = h_;
        sl[(1+i)*PR + lane] = f2bf(v - bf2f(h_));
      }
    }
    if (wid == 2 && kband < 15 && e < NEP-1) {  // bottom halo <- down-neighbor's top rows
      int f = -1, guard = 0;
      while (f < e && ++guard < (1<<17)) {
        if (lane == 0) f = ATOM_LD(&ws->flags[wg+1]);
        f = __shfl(f, 0);
        if (f < e) __builtin_amdgcn_s_sleep(1);
      }
      asm volatile("" ::: "memory");
#pragma unroll
      for (int i = 0; i < 8; ++i) {
        // haloT[i] = absrow a+32+i -> slot 40+i
        float v = __uint_as_float(ATOM_LD(&ws->haloT[wg+1][par][i*64 + lane]));
        u16 h_ = f2bf(v);
        sh[(40+i)*PR + lane] = h_;
        sl[(40+i)*PR + lane] = f2bf(v - bf2f(h_));
      }
    }
    if (wid >= 4) {
      // flush epoch's 7 output columns (bf16 stage -> f32 global), 256 threads
      const int thr = tid - 256;
#pragma unroll 1
      for (int i = 0; i < 8; ++i) {
        const int ci = thr + 256*i;
        const int c = ci & 63, row = ci >> 6;
        float* go = out + (size_t)(b*C64 + c)*HWp + (size_t)(a + row)*512 + (e*T7 + 1);
#pragma unroll
        for (int dc = 0; dc < T7; ++dc)
          go[dc] = bf2f(ostage[(row*T7 + dc)*64 + c]);
      }
    }
    __syncthreads();   // state consistent; flush complete before next ostage writes
  }
}

extern "C" void kernel_launch(void* const* d_in, const int* in_sizes, int n_in,
                              void* d_out, int out_size, void* d_ws, size_t ws_size,
                              hipStream_t stream) {
  const float* feat = (const float*)d_in[0];
  const float* wih  = (const float*)d_in[1];
  const float* whh  = (const float*)d_in[2];
  const float* bih  = (const float*)d_in[3];
  const float* bhh  = (const float*)d_in[4];
  float* out = (float*)d_out;
  Ws* ws = (Ws*)d_ws;

  reset_flags<<<1, 64, 0, stream>>>(ws->flags);
  gru_scan<<<NWG, 512, 0, stream>>>(feat, wih, whh, bih, bhh, out, ws);
}

// Round 7
// 4132.676 us; speedup vs baseline: 4.1630x; 4.1630x over previous
//
#include <hip/hip_runtime.h>

typedef short short8 __attribute__((ext_vector_type(8)));
typedef float f32x4 __attribute__((ext_vector_type(4)));
typedef unsigned short u16;
typedef unsigned int u32;

#define C64 64
#define HWp (512*512)
#define NWG 64
#define PR 72      // LDS row stride in u16 (144 B; 36 words, 36%8==4 -> b128 conflict-free)
#define NROW 48    // rows computed per step (3 MFMA M-tiles)
#define SLOTS 50   // state window: absrows a-8 .. a+41
#define T7 7       // columns per epoch (511 = 7*73)
#define NEP 73

struct Ws {
  int flags[NWG][32];        // one 128B line per band
  u32 haloT[NWG][2][8*64];   // band's owned rows absr a..a+7, f32 bits
  u32 haloB[NWG][2][7*64];   // band's owned rows absr a+25..a+31, f32 bits
};

__device__ __forceinline__ u16 f2bf(float f){
  u32 u = __float_as_uint(f);
  u += 0x7fffu + ((u >> 16) & 1u);
  return (u16)(u >> 16);
}
__device__ __forceinline__ float bf2f(u16 h){ return __uint_as_float(((u32)h) << 16); }
__device__ __forceinline__ f32x4 splat4(float x){ f32x4 v = {x,x,x,x}; return v; }
__device__ __forceinline__ float sigm(float x){ return 1.f/(1.f + __expf(-x)); }
__device__ __forceinline__ float tanh_(float x){ float e = __expf(2.f*x); return 1.f - 2.f/(e + 1.f); }

#define MFMA16(a,b,c) __builtin_amdgcn_mfma_f32_16x16x32_bf16(a,b,c,0,0,0)
#define ATOM_ST(p,v) __hip_atomic_store((p),(v),__ATOMIC_RELAXED,__HIP_MEMORY_SCOPE_AGENT)
#define ATOM_LD(p)   __hip_atomic_load((p),__ATOMIC_RELAXED,__HIP_MEMORY_SCOPE_AGENT)

__global__ void reset_flags(int* flags) {
  if (threadIdx.x < NWG) flags[threadIdx.x * 32] = -1;
}

__global__ __launch_bounds__(256, 1)
void gru_scan(const float* __restrict__ feat,
              const float* __restrict__ w_ih,
              const float* __restrict__ w_hh,
              const float* __restrict__ b_ih,
              const float* __restrict__ b_hh,
              float* __restrict__ out,
              Ws* __restrict__ ws)
{
  // ping-pong state: slot s = absrow (a-8+s), hi/lo bf16 planes
  __shared__ __align__(16) u16 sh[2*SLOTS*PR], sl[2*SLOTS*PR];
  // ping-pong current feat column, rows m=0..47 (absrow a-7+m)
  __shared__ __align__(16) u16 uh[2*NROW*PR], ul[2*NROW*PR];

  const int tid  = threadIdx.x;
  const int wg   = blockIdx.x;
  const int b    = wg >> 4;
  const int kband= wg & 15;
  const int a    = kband * 32;          // first owned row
  const int lane = tid & 63;
  const int wid  = tid >> 6;            // 0..3 = ch-quarter
  const int ln16 = lane & 15;
  const int kgrp = lane >> 4;
  const int ch   = wid*16 + ln16;       // output channel of this thread

  // ---- weights (hi+lo) in registers ----
  short8 BihH[3][6], BihL[3][6], BhhH[3][2], BhhL[3][2];
#pragma unroll
  for (int g = 0; g < 3; ++g) {
    const int n = g*64 + ch;
#pragma unroll
    for (int kk = 0; kk < 6; ++kk) {
      short8 vh, vl;
#pragma unroll
      for (int j = 0; j < 8; ++j) {
        float wv = w_ih[n*192 + kk*32 + kgrp*8 + j];
        u16 h = f2bf(wv); vh[j] = (short)h; vl[j] = (short)f2bf(wv - bf2f(h));
      }
      BihH[g][kk] = vh; BihL[g][kk] = vl;
    }
#pragma unroll
    for (int kt = 0; kt < 2; ++kt) {
      short8 vh, vl;
#pragma unroll
      for (int j = 0; j < 8; ++j) {
        float wv = w_hh[n*64 + kt*32 + kgrp*8 + j];
        u16 h = f2bf(wv); vh[j] = (short)h; vl[j] = (short)f2bf(wv - bf2f(h));
      }
      BhhH[g][kt] = vh; BhhL[g][kt] = vl;
    }
  }
  const float biasR  = b_ih[ch]       + b_hh[ch];
  const float biasZ  = b_ih[64 + ch]  + b_hh[64 + ch];
  const float biasI  = b_ih[128 + ch];
  const float biasHn = b_hh[128 + ch];

  // ---- loader mapping: thread loads 12 rows of one channel ----
  const int lch = tid & 63;
  const int lr0 = (tid >> 6) * 12;
  const float* fbase = feat + (size_t)(b*C64 + lch)*HWp;

  // ---- init ----
  for (int i = tid; i < 2*SLOTS*PR; i += 256) { sh[i] = 0; sl[i] = 0; }
  __syncthreads();
  // column 0 -> state buf0 + out passthrough; column 1 -> uh/ul buf0
#pragma unroll
  for (int i = 0; i < 12; ++i) {
    const int m = lr0 + i, absr = a - 7 + m;
    if ((unsigned)absr < 512u) {
      float v = fbase[(size_t)absr*512];
      u16 h_ = f2bf(v);
      sh[(m+1)*PR + lch] = h_;
      sl[(m+1)*PR + lch] = f2bf(v - bf2f(h_));
      if (m >= 7 && m < 39) out[(size_t)(b*C64 + lch)*HWp + (size_t)absr*512] = v;
      float v1 = fbase[(size_t)absr*512 + 1];
      u16 h1 = f2bf(v1);
      uh[m*PR + lch] = h1;
      ul[m*PR + lch] = f2bf(v1 - bf2f(h1));
    } else {
      uh[m*PR + lch] = 0; ul[m*PR + lch] = 0;
    }
  }
  __syncthreads();

  // ---- epoch loop ----
  for (int e = 0; e < NEP; ++e) {
    const int par = e & 1;
#pragma unroll 1
    for (int d = 0; d < T7; ++d) {
      const int n    = e*T7 + d;        // global step
      const int w    = n + 1;           // column being computed
      const int p    = n & 1;
      const u16* shp = sh + p*SLOTS*PR;
      const u16* slp = sl + p*SLOTS*PR;
      const u16* uhp = uh + p*NROW*PR;
      const u16* ulp = ul + p*NROW*PR;
      u16* shn = sh + (p^1)*SLOTS*PR;
      u16* sln = sl + (p^1)*SLOTS*PR;
      u16* uhn = uh + (p^1)*NROW*PR;
      u16* uln = ul + (p^1)*NROW*PR;

      // prefetch feat column w+1 (consumed in writeback phase)
      float cv[12];
      {
        const int wn = (w < 511) ? w + 1 : 511;
#pragma unroll
        for (int i = 0; i < 12; ++i) {
          const int absr = a - 7 + lr0 + i;
          cv[i] = ((unsigned)absr < 512u) ? fbase[(size_t)absr*512 + wn] : 0.f;
        }
      }

      // ---- compute: 3 M-tiles, split hi/lo accumulator chains ----
      float hnv[3][4];
#pragma unroll
      for (int t = 0; t < 3; ++t) {
        f32x4 aRH = splat4(biasR), aZH = splat4(biasZ);
        f32x4 aIH = splat4(biasI), aHH = splat4(biasHn);
        f32x4 aRL = splat4(0.f), aZL = splat4(0.f);
        f32x4 aIL = splat4(0.f), aHL = splat4(0.f);
        short8 Xh[2], Xl[2];
#pragma unroll
        for (int kt = 0; kt < 2; ++kt) {
          const int ro = (t*16 + ln16)*PR + kt*32 + kgrp*8;
          Xh[kt] = *(const short8*)&uhp[ro];
          Xl[kt] = *(const short8*)&ulp[ro];
        }
#pragma unroll
        for (int kk = 0; kk < 6; ++kk) {
          const int ro = (t*16 + ln16 + (kk>>1))*PR + (kk&1)*32 + kgrp*8;
          short8 Ah = *(const short8*)&shp[ro];
          short8 Al = *(const short8*)&slp[ro];
          aRH = MFMA16(Ah, BihH[0][kk], aRH);
          aRL = MFMA16(Al, BihH[0][kk], aRL);
          aRL = MFMA16(Ah, BihL[0][kk], aRL);
          aZH = MFMA16(Ah, BihH[1][kk], aZH);
          aZL = MFMA16(Al, BihH[1][kk], aZL);
          aZL = MFMA16(Ah, BihL[1][kk], aZL);
          aIH = MFMA16(Ah, BihH[2][kk], aIH);
          aIL = MFMA16(Al, BihH[2][kk], aIL);
          aIL = MFMA16(Ah, BihL[2][kk], aIL);
        }
#pragma unroll
        for (int kt = 0; kt < 2; ++kt) {
          aRH = MFMA16(Xh[kt], BhhH[0][kt], aRH);
          aRL = MFMA16(Xl[kt], BhhH[0][kt], aRL);
          aRL = MFMA16(Xh[kt], BhhL[0][kt], aRL);
          aZH = MFMA16(Xh[kt], BhhH[1][kt], aZH);
          aZL = MFMA16(Xl[kt], BhhH[1][kt], aZL);
          aZL = MFMA16(Xh[kt], BhhL[1][kt], aZL);
          aHH = MFMA16(Xh[kt], BhhH[2][kt], aHH);
          aHL = MFMA16(Xl[kt], BhhH[2][kt], aHL);
          aHL = MFMA16(Xh[kt], BhhL[2][kt], aHL);
        }
#pragma unroll
        for (int j = 0; j < 4; ++j) {
          const int m = t*16 + kgrp*4 + j;
          float r = sigm(aRH[j] + aRL[j]);
          float z = sigm(aZH[j] + aZL[j]);
          float nn = tanh_(aIH[j] + aIL[j] + r * (aHH[j] + aHL[j]));
          float cur = bf2f(uhp[m*PR + ch]) + bf2f(ulp[m*PR + ch]);
          hnv[t][j] = (1.f - z)*nn + z*cur;
        }
      }

      // ---- writeback to the OTHER buffers (no barrier needed before) ----
#pragma unroll
      for (int t = 0; t < 3; ++t)
#pragma unroll
        for (int j = 0; j < 4; ++j) {
          const int m = t*16 + kgrp*4 + j;
          const int absr = a - 7 + m;
          const float v = hnv[t][j];
          if ((unsigned)absr < 512u) {   // keeps out-of-image slots zero
            u16 h_ = f2bf(v);
            shn[(m+1)*PR + ch] = h_;
            sln[(m+1)*PR + ch] = f2bf(v - bf2f(h_));
            if (m >= 7 && m < 39)        // owned row: direct global store
              out[(size_t)(b*C64 + ch)*HWp + (size_t)absr*512 + w] = v;
          }
          if (d == T7-1 && e < NEP-1) {  // epoch-boundary halo send (exact f32)
            if (m >= 7 && m <= 14)
              ATOM_ST(&ws->haloT[wg][par][(m-7)*64 + ch], __float_as_uint(v));
            if (m >= 32 && m <= 38)
              ATOM_ST(&ws->haloB[wg][par][(m-32)*64 + ch], __float_as_uint(v));
          }
        }
      // next feat column into the other u-buffer
#pragma unroll
      for (int i = 0; i < 12; ++i) {
        const int m = lr0 + i;
        u16 h_ = f2bf(cv[i]);
        uhn[m*PR + lch] = h_;
        uln[m*PR + lch] = f2bf(cv[i] - bf2f(h_));
      }
      if (d < T7-1) __syncthreads();     // the single per-step barrier
    }

    // ---- epoch boundary ----
    asm volatile("s_waitcnt vmcnt(0)" ::: "memory");  // drain halo sends (+ stores)
    __syncthreads();
    if (e < NEP-1) {
      if (tid == 0) ATOM_ST(&ws->flags[wg][0], e);
      const int pnext = (e + 1) & 1;                  // (e+1)*7 mod 2
      u16* shx = sh + pnext*SLOTS*PR;
      u16* slx = sl + pnext*SLOTS*PR;
      if (wid == 1 && kband > 0) {        // top halo <- up-neighbor's bottom rows
        int f = -1, guard = 0;
        while (f < e && ++guard < (1<<17)) {
          if (lane == 0) f = ATOM_LD(&ws->flags[wg-1][0]);
          f = __shfl(f, 0);
          if (f < e) __builtin_amdgcn_s_sleep(1);
        }
        asm volatile("" ::: "memory");
#pragma unroll
        for (int i = 0; i < 7; ++i) {     // absrow a-7+i -> slot 1+i
          float v = __uint_as_float(ATOM_LD(&ws->haloB[wg-1][par][i*64 + lane]));
          u16 h_ = f2bf(v);
          shx[(1+i)*PR + lane] = h_;
          slx[(1+i)*PR + lane] = f2bf(v - bf2f(h_));
        }
      }
      if (wid == 2 && kband < 15) {       // bottom halo <- down-neighbor's top rows
        int f = -1, guard = 0;
        while (f < e && ++guard < (1<<17)) {
          if (lane == 0) f = ATOM_LD(&ws->flags[wg+1][0]);
          f = __shfl(f, 0);
          if (f < e) __builtin_amdgcn_s_sleep(1);
        }
        asm volatile("" ::: "memory");
#pragma unroll
        for (int i = 0; i < 8; ++i) {     // absrow a+32+i -> slot 40+i
          float v = __uint_as_float(ATOM_LD(&ws->haloT[wg+1][par][i*64 + lane]));
          u16 h_ = f2bf(v);
          shx[(40+i)*PR + lane] = h_;
          slx[(40+i)*PR + lane] = f2bf(v - bf2f(h_));
        }
      }
    }
    __syncthreads();   // halos + last writeback visible before next epoch
  }
}

extern "C" void kernel_launch(void* const* d_in, const int* in_sizes, int n_in,
                              void* d_out, int out_size, void* d_ws, size_t ws_size,
                              hipStream_t stream) {
  const float* feat = (const float*)d_in[0];
  const float* wih  = (const float*)d_in[1];
  const float* whh  = (const float*)d_in[2];
  const float* bih  = (const float*)d_in[3];
  const float* bhh  = (const float*)d_in[4];
  float* out = (float*)d_out;
  Ws* ws = (Ws*)d_ws;

  reset_flags<<<1, 64, 0, stream>>>((int*)ws->flags);
  gru_scan<<<NWG, 256, 0, stream>>>(feat, wih, whh, bih, bhh, out, ws);
}

// Round 8
// 3115.813 us; speedup vs baseline: 5.5217x; 1.3264x over previous
//
#include <hip/hip_runtime.h>

typedef short short8 __attribute__((ext_vector_type(8)));
typedef float f32x4 __attribute__((ext_vector_type(4)));
typedef unsigned short u16;
typedef unsigned int u32;

#define C64 64
#define HWp (512*512)
#define NWG 128    // 4 images x 32 bands of 16 rows
#define PR 72      // LDS row stride in u16 (144 B)
#define NROW 32    // rows computed per step (2 MFMA M-tiles)
#define SLOTS 34   // state window: absrows a-8 .. a+25
#define T7 7       // columns per epoch (511 = 7*73)
#define NEP 73

struct Ws {
  int flags[NWG][32];        // one 128B line per band
  u32 haloT[NWG][2][8*64];   // band's rows absr a..a+7 (m=7..14), f32 bits
  u32 haloB[NWG][2][7*64];   // band's rows absr a+9..a+15 (m=16..22), f32 bits
};

__device__ __forceinline__ u16 f2bf(float f){
  u32 u = __float_as_uint(f);
  u += 0x7fffu + ((u >> 16) & 1u);
  return (u16)(u >> 16);
}
__device__ __forceinline__ float bf2f(u16 h){ return __uint_as_float(((u32)h) << 16); }
__device__ __forceinline__ f32x4 splat4(float x){ f32x4 v = {x,x,x,x}; return v; }
__device__ __forceinline__ float sigm(float x){ return 1.f/(1.f + __expf(-x)); }
__device__ __forceinline__ float tanh_(float x){ float e = __expf(2.f*x); return 1.f - 2.f/(e + 1.f); }

#define MFMA16(a,b,c) __builtin_amdgcn_mfma_f32_16x16x32_bf16(a,b,c,0,0,0)
#define ATOM_ST(p,v) __hip_atomic_store((p),(v),__ATOMIC_RELAXED,__HIP_MEMORY_SCOPE_AGENT)
#define ATOM_LD(p)   __hip_atomic_load((p),__ATOMIC_RELAXED,__HIP_MEMORY_SCOPE_AGENT)

__global__ void reset_flags(int* flags) {
  if (threadIdx.x < NWG) flags[threadIdx.x * 32] = -1;
}

__global__ __launch_bounds__(256, 1)
void gru_scan(const float* __restrict__ feat,
              const float* __restrict__ w_ih,
              const float* __restrict__ w_hh,
              const float* __restrict__ b_ih,
              const float* __restrict__ b_hh,
              float* __restrict__ out,
              Ws* __restrict__ ws)
{
  // ping-pong state: slot s = absrow (a-8+s), hi/lo bf16 planes
  __shared__ __align__(16) u16 sh[2*SLOTS*PR], sl[2*SLOTS*PR];
  // ping-pong current feat column, rows m=0..31 (absrow a-7+m)
  __shared__ __align__(16) u16 uh[2*NROW*PR], ul[2*NROW*PR];
  // output stage: [owned row 0..15][col 0..6][ch 0..63] bf16
  __shared__ u16 ostage[16*T7*64];

  const int tid  = threadIdx.x;
  const int wg   = blockIdx.x;
  const int b    = wg >> 5;
  const int kband= wg & 31;
  const int a    = kband * 16;          // first owned row
  const int lane = tid & 63;
  const int wid  = tid >> 6;            // 0..3 = ch-quarter
  const int ln16 = lane & 15;
  const int kgrp = lane >> 4;
  const int ch   = wid*16 + ln16;       // output channel of this thread

  // ---- weights (hi+lo) in registers ----
  short8 BihH[3][6], BihL[3][6], BhhH[3][2], BhhL[3][2];
#pragma unroll
  for (int g = 0; g < 3; ++g) {
    const int n = g*64 + ch;
#pragma unroll
    for (int kk = 0; kk < 6; ++kk) {
      short8 vh, vl;
#pragma unroll
      for (int j = 0; j < 8; ++j) {
        float wv = w_ih[n*192 + kk*32 + kgrp*8 + j];
        u16 h = f2bf(wv); vh[j] = (short)h; vl[j] = (short)f2bf(wv - bf2f(h));
      }
      BihH[g][kk] = vh; BihL[g][kk] = vl;
    }
#pragma unroll
    for (int kt = 0; kt < 2; ++kt) {
      short8 vh, vl;
#pragma unroll
      for (int j = 0; j < 8; ++j) {
        float wv = w_hh[n*64 + kt*32 + kgrp*8 + j];
        u16 h = f2bf(wv); vh[j] = (short)h; vl[j] = (short)f2bf(wv - bf2f(h));
      }
      BhhH[g][kt] = vh; BhhL[g][kt] = vl;
    }
  }
  const float biasR  = b_ih[ch]       + b_hh[ch];
  const float biasZ  = b_ih[64 + ch]  + b_hh[64 + ch];
  const float biasI  = b_ih[128 + ch];
  const float biasHn = b_hh[128 + ch];

  // ---- loader mapping: thread owns 8 rows of one channel ----
  const int lch = tid & 63;
  const int lr0 = (tid >> 6) * 8;
  const float* fbase = feat + (size_t)(b*C64 + lch)*HWp;

  // epoch-batched feat columns: cv[i][j] = feat[absr(lr0+i)][wbase+j]
  float cv[8][T7];

  // ---- init ----
  for (int i = tid; i < 2*SLOTS*PR; i += 256) { sh[i] = 0; sl[i] = 0; }
  __syncthreads();
  // column 0 -> state buf0 + out passthrough
#pragma unroll
  for (int i = 0; i < 8; ++i) {
    const int m = lr0 + i, absr = a - 7 + m;
    if ((unsigned)absr < 512u) {
      float v = fbase[(size_t)absr*512];
      u16 h_ = f2bf(v);
      sh[(m+1)*PR + lch] = h_;
      sl[(m+1)*PR + lch] = f2bf(v - bf2f(h_));
      if (m >= 7 && m < 23) out[(size_t)(b*C64 + lch)*HWp + (size_t)absr*512] = v;
    }
  }
  // prologue: load epoch-0 columns 1..7, prime u[0] with column 1
#pragma unroll
  for (int i = 0; i < 8; ++i) {
    const int absr = a - 7 + lr0 + i;
#pragma unroll
    for (int j = 0; j < T7; ++j)
      cv[i][j] = ((unsigned)absr < 512u) ? fbase[(size_t)absr*512 + 1 + j] : 0.f;
  }
#pragma unroll
  for (int i = 0; i < 8; ++i) {
    const int m = lr0 + i;
    float v = cv[i][0];
    u16 h_ = f2bf(v);
    uh[m*PR + lch] = h_;
    ul[m*PR + lch] = f2bf(v - bf2f(h_));
#pragma unroll
    for (int j = 0; j < 6; ++j) cv[i][j] = cv[i][j+1];
  }
  __syncthreads();

  // ---- epoch loop ----
  for (int e = 0; e < NEP; ++e) {
    const int par = e & 1;
#pragma unroll 1
    for (int d = 0; d < T7; ++d) {
      const int p = (e + d) & 1;          // parity of step n=7e+d
      const u16* shp = sh + p*SLOTS*PR;
      const u16* slp = sl + p*SLOTS*PR;
      const u16* uhp = uh + p*NROW*PR;
      const u16* ulp = ul + p*NROW*PR;
      u16* shn = sh + (p^1)*SLOTS*PR;
      u16* sln = sl + (p^1)*SLOTS*PR;
      u16* uhn = uh + (p^1)*NROW*PR;
      u16* uln = ul + (p^1)*NROW*PR;

      // ---- compute: 2 M-tiles, split hi/lo accumulator chains ----
      float hnv[2][4];
#pragma unroll
      for (int t = 0; t < 2; ++t) {
        f32x4 aRH = splat4(biasR), aZH = splat4(biasZ);
        f32x4 aIH = splat4(biasI), aHH = splat4(biasHn);
        f32x4 aRL = splat4(0.f), aZL = splat4(0.f);
        f32x4 aIL = splat4(0.f), aHL = splat4(0.f);
        short8 Xh[2], Xl[2];
#pragma unroll
        for (int kt = 0; kt < 2; ++kt) {
          const int ro = (t*16 + ln16)*PR + kt*32 + kgrp*8;
          Xh[kt] = *(const short8*)&uhp[ro];
          Xl[kt] = *(const short8*)&ulp[ro];
        }
#pragma unroll
        for (int kk = 0; kk < 6; ++kk) {
          const int ro = (t*16 + ln16 + (kk>>1))*PR + (kk&1)*32 + kgrp*8;
          short8 Ah = *(const short8*)&shp[ro];
          short8 Al = *(const short8*)&slp[ro];
          aRH = MFMA16(Ah, BihH[0][kk], aRH);
          aRL = MFMA16(Al, BihH[0][kk], aRL);
          aRL = MFMA16(Ah, BihL[0][kk], aRL);
          aZH = MFMA16(Ah, BihH[1][kk], aZH);
          aZL = MFMA16(Al, BihH[1][kk], aZL);
          aZL = MFMA16(Ah, BihL[1][kk], aZL);
          aIH = MFMA16(Ah, BihH[2][kk], aIH);
          aIL = MFMA16(Al, BihH[2][kk], aIL);
          aIL = MFMA16(Ah, BihL[2][kk], aIL);
        }
#pragma unroll
        for (int kt = 0; kt < 2; ++kt) {
          aRH = MFMA16(Xh[kt], BhhH[0][kt], aRH);
          aRL = MFMA16(Xl[kt], BhhH[0][kt], aRL);
          aRL = MFMA16(Xh[kt], BhhL[0][kt], aRL);
          aZH = MFMA16(Xh[kt], BhhH[1][kt], aZH);
          aZL = MFMA16(Xl[kt], BhhH[1][kt], aZL);
          aZL = MFMA16(Xh[kt], BhhL[1][kt], aZL);
          aHH = MFMA16(Xh[kt], BhhH[2][kt], aHH);
          aHL = MFMA16(Xl[kt], BhhH[2][kt], aHL);
          aHL = MFMA16(Xh[kt], BhhL[2][kt], aHL);
        }
#pragma unroll
        for (int j = 0; j < 4; ++j) {
          const int m = t*16 + kgrp*4 + j;
          float r = sigm(aRH[j] + aRL[j]);
          float z = sigm(aZH[j] + aZL[j]);
          float nn = tanh_(aIH[j] + aIL[j] + r * (aHH[j] + aHL[j]));
          float cur = bf2f(uhp[m*PR + ch]) + bf2f(ulp[m*PR + ch]);
          hnv[t][j] = (1.f - z)*nn + z*cur;
        }
      }

      // ---- writeback to the other state buffer + ostage (+halo sends at d=6) ----
#pragma unroll
      for (int t = 0; t < 2; ++t)
#pragma unroll
        for (int j = 0; j < 4; ++j) {
          const int m = t*16 + kgrp*4 + j;
          const int absr = a - 7 + m;
          const float v = hnv[t][j];
          if ((unsigned)absr < 512u) {     // keeps out-of-image slots zero
            u16 h_ = f2bf(v);
            shn[(m+1)*PR + ch] = h_;
            sln[(m+1)*PR + ch] = f2bf(v - bf2f(h_));
          }
          if (m >= 7 && m < 23)
            ostage[((m-7)*T7 + d)*64 + ch] = f2bf(v);
          if (d == T7-1 && e < NEP-1) {    // epoch-boundary halo send (exact f32)
            if (m >= 7 && m <= 14)         // absr a..a+7
              ATOM_ST(&ws->haloT[wg][par][(m-7)*64 + ch], __float_as_uint(v));
            if (m >= 16 && m <= 22)        // absr a+9..a+15
              ATOM_ST(&ws->haloB[wg][par][(m-16)*64 + ch], __float_as_uint(v));
          }
        }
      if (d < T7-1) {
        // u[p^1] <- next column from register stage; rotate (compile-time idx)
#pragma unroll
        for (int i = 0; i < 8; ++i) {
          const int m = lr0 + i;
          float v = cv[i][0];
          u16 h_ = f2bf(v);
          uhn[m*PR + lch] = h_;
          uln[m*PR + lch] = f2bf(v - bf2f(h_));
#pragma unroll
          for (int j = 0; j < 6; ++j) cv[i][j] = cv[i][j+1];
        }
        __syncthreads();                   // the single per-step barrier
      }
    }

    // ---- epoch boundary ----
    asm volatile("s_waitcnt vmcnt(0)" ::: "memory");  // drain halo sends
    __syncthreads();
    if (e < NEP-1 && tid == 0) ATOM_ST(&ws->flags[wg][0], e);

    // issue next epoch's feat loads EARLY (latency hides under flush/handshake)
    if (e < NEP-1) {
      const int wbase = 7*(e+1) + 1;
#pragma unroll
      for (int i = 0; i < 8; ++i) {
        const int absr = a - 7 + lr0 + i;
#pragma unroll
        for (int j = 0; j < T7; ++j)
          cv[i][j] = ((unsigned)absr < 512u) ? fbase[(size_t)absr*512 + wbase + j] : 0.f;
      }
    }

    if (wid == 0 || wid == 3) {
      // flush epoch's 7 output columns (bf16 stage -> f32 global)
      const int thr = (wid == 0) ? lane : 64 + lane;
#pragma unroll 1
      for (int i = 0; i < 8; ++i) {
        const int ci = thr + 128*i;
        const int c = ci & 63, row = ci >> 6;          // row in [0,16)
        float* go = out + (size_t)(b*C64 + c)*HWp + (size_t)(a + row)*512 + (e*T7 + 1);
#pragma unroll
        for (int dc = 0; dc < T7; ++dc)
          go[dc] = bf2f(ostage[(row*T7 + dc)*64 + c]);
      }
    } else if (e < NEP-1) {
      const int pn = (e + 1) & 1;
      u16* shx = sh + pn*SLOTS*PR;
      u16* slx = sl + pn*SLOTS*PR;
      if (wid == 1 && kband > 0) {        // top halo <- up-neighbor's haloB
        int f = -1, guard = 0;
        while (f < e && ++guard < (1<<17)) {
          if (lane == 0) f = ATOM_LD(&ws->flags[wg-1][0]);
          f = __shfl(f, 0);
          if (f < e) __builtin_amdgcn_s_sleep(1);
        }
        asm volatile("" ::: "memory");
#pragma unroll
        for (int i = 0; i < 7; ++i) {     // absrow a-7+i -> slot 1+i
          float v = __uint_as_float(ATOM_LD(&ws->haloB[wg-1][par][i*64 + lane]));
          u16 h_ = f2bf(v);
          shx[(1+i)*PR + lane] = h_;
          slx[(1+i)*PR + lane] = f2bf(v - bf2f(h_));
        }
      }
      if (wid == 2 && kband < 31) {       // bottom halo <- down-neighbor's haloT
        int f = -1, guard = 0;
        while (f < e && ++guard < (1<<17)) {
          if (lane == 0) f = ATOM_LD(&ws->flags[wg+1][0]);
          f = __shfl(f, 0);
          if (f < e) __builtin_amdgcn_s_sleep(1);
        }
        asm volatile("" ::: "memory");
#pragma unroll
        for (int i = 0; i < 8; ++i) {     // absrow a+16+i -> slot 24+i
          float v = __uint_as_float(ATOM_LD(&ws->haloT[wg+1][par][i*64 + lane]));
          u16 h_ = f2bf(v);
          shx[(24+i)*PR + lane] = h_;
          slx[(24+i)*PR + lane] = f2bf(v - bf2f(h_));
        }
      }
    }

    if (e < NEP-1) {
      // prime u[(e+1)&1] with first column of next epoch; rotate
      const int pn = (e + 1) & 1;
      u16* uhx = uh + pn*NROW*PR;
      u16* ulx = ul + pn*NROW*PR;
#pragma unroll
      for (int i = 0; i < 8; ++i) {
        const int m = lr0 + i;
        float v = cv[i][0];
        u16 h_ = f2bf(v);
        uhx[m*PR + lch] = h_;
        ulx[m*PR + lch] = f2bf(v - bf2f(h_));
#pragma unroll
        for (int j = 0; j < 6; ++j) cv[i][j] = cv[i][j+1];
      }
    }
    __syncthreads();   // halos + u primed + flush done before next epoch's steps
  }
}

extern "C" void kernel_launch(void* const* d_in, const int* in_sizes, int n_in,
                              void* d_out, int out_size, void* d_ws, size_t ws_size,
                              hipStream_t stream) {
  const float* feat = (const float*)d_in[0];
  const float* wih  = (const float*)d_in[1];
  const float* whh  = (const float*)d_in[2];
  const float* bih  = (const float*)d_in[3];
  const float* bhh  = (const float*)d_in[4];
  float* out = (float*)d_out;
  Ws* ws = (Ws*)d_ws;

  reset_flags<<<1, NWG, 0, stream>>>((int*)ws->flags);
  gru_scan<<<NWG, 256, 0, stream>>>(feat, wih, whh, bih, bhh, out, ws);
}